// Round 4
// baseline (343.383 us; speedup 1.0000x reference)
//
#include <hip/hip_runtime.h>

// ---------------------------------------------------------------------------
// STCAOutputLayer: h = x@w (bf16 MFMA GEMM); E==0 identically (spk never set),
// out[b,t,d] = (M_t - S_t)*inv_norm[d] - bias[d],
// M_t = dm*(M_{t-1}+h_t), S_t = ds*(S_{t-1}+h_t); loss = 0.5*mean(out^2).
// Shapes: B=32 T=500 IN=2048 OUT=1024; M=B*T=16000, N=1024, K=2048.
//
// R3-R5 post-mortem: three schedules all pinned at MfmaUtil ~33% because the
// block-wide barriers serialized the LDS burst (96KB reads/kt ~ 900cy) against
// the MFMA burst (310cy/kt): 33% = 310/940. R6:
//  (1) convert_x FUSED into GEMM A-staging (f32 loads -> cvt -> swizzled
//      ds_write): deletes a 31us kernel + ~130MB HBM traffic.
//  (2) one barrier per phase (post-MFMA only): reads/stages of phase p
//      overlap other waves' MFMAs (2 waves/SIMD). 4 LDS buffers, BK=32,
//      counted vmcnt(6) steady (tail ladder 2->2->0), stage lead 3 tiles.
// Hazards (derived, see comments): stage target buf[(t+3)&3] last read at
// phase2(t-1), drained by lgkmcnt(0)+post-barrier before any stage of t+3
// issues; vmcnt(6) at ph1(t) lands A-regs(t+3) and B(t+2) (everything older),
// two barriers before first read of tile t+1 makes it block-wide.
// ---------------------------------------------------------------------------

typedef __bf16 bf16x8 __attribute__((ext_vector_type(8)));
typedef __bf16 bf16x4 __attribute__((ext_vector_type(4)));
typedef float  f32x4  __attribute__((ext_vector_type(4)));

#define BDIM 32
#define TDIM 500
#define INDIM 2048
#define OUTDIM 1024
#define MROWS 16000            // B*T
#define NCHUNK 25              // scan chunks
#define CHLEN 20               // 25*20 = 500
#define OUT_ELEMS 16384000     // B*T*OUT

// ---- global -> LDS async copy, 16B per lane, LDS dest = base + lane*16 ----
__device__ __forceinline__ void gld_lds16(const void* g, void* l) {
    __builtin_amdgcn_global_load_lds(
        (const __attribute__((address_space(1))) unsigned int*)g,
        (__attribute__((address_space(3))) unsigned int*)l, 16, 0, 0);
}

// ---------------------------------------------------------------------------
// w [K=2048][N=1024] fp32 -> wbt [N][K] bf16, with fused norm[d]=sum_c w^2
__global__ void transpose_w(const float* __restrict__ w, __bf16* __restrict__ wbt,
                            float* __restrict__ normAcc) {
    __shared__ float tile[32][33];
    __shared__ float red[8][33];
    const int tx = threadIdx.x;        // 0..31
    const int ty = threadIdx.y;        // 0..7
    const int d0 = blockIdx.x * 32;    // N tile
    const int c0 = blockIdx.y * 32;    // K tile
    float s = 0.f;
#pragma unroll
    for (int i = 0; i < 4; ++i) {
        int c = c0 + ty + i * 8;
        float v = w[(size_t)c * OUTDIM + d0 + tx];
        tile[ty + i * 8][tx] = v;
        s += v * v;
    }
    red[ty][tx] = s;
    __syncthreads();
#pragma unroll
    for (int i = 0; i < 4; ++i) {
        int d = d0 + ty + i * 8;
        wbt[(size_t)d * INDIM + c0 + tx] = (__bf16)tile[tx][ty + i * 8];
    }
    if (ty == 0) {
        float t = red[0][tx] + red[1][tx] + red[2][tx] + red[3][tx]
                + red[4][tx] + red[5][tx] + red[6][tx] + red[7][tx];
        atomicAdd(&normAcc[d0 + tx], t);
    }
}

// ---------------------------------------------------------------------------
// GEMM + fused f32->bf16 A conversion.
// H[m][n] = sum_k A[m][k]*Bt[n][k]; A is f32 (x), Bt bf16, H bf16 (fp32 acc).
// BM=BN=256, BK=32, 8 waves (wm 0..1 x wn 0..3), wave tile 128x64 (8x4 frags
// of 16x16x32). 4 buffers x (A 16KB + B 16KB) = 128KB LDS.
// Per K-tile t, two phases:
//  ph1: issue 4x f32x4 A-loads(t+4); vmcnt(6); cvt+2x ds_write A(t+3);
//       8 ds_read (a0-3,b0-3); lgkm(0); 16 MFMA; s_barrier
//  ph2: 2x gld_lds B(t+3); 4 ds_read (a4-7); lgkm(0); 16 MFMA; s_barrier
// vm-op stream/kt: Ald x4 (ph1), Bgld x2 (ph2) -> vmcnt(6) at ph1(t) leaves
// {B(t+2)x2, Ald(t+4)x4}: lands Ald(t+3) (wb input) and B(t+1) (next reads).
// Tail: t==60,61 -> vmcnt(2); t==62 -> vmcnt(0); t==63 none.
// XOR swizzle (proven R3-R5): phys seg = logical seg ^ ((row>>1)&3) on 64B
// rows of 4x16B segs -> 2-way (free) on both ds_read_b128 and writes.
__global__ __launch_bounds__(512, 2) void gemm_fused(
    const float* __restrict__ A,    // [16000][2048] f32 (x)
    const __bf16* __restrict__ Bt,  // [1024][2048]
    __bf16* __restrict__ H)         // [16000][1024]
{
    constexpr int K  = INDIM;
    constexpr int NT = K / 32;                       // 64 K-tiles
    __shared__ __align__(16) __bf16 As[4][256 * 32]; // 4 x 16KB
    __shared__ __align__(16) __bf16 Bs[4][256 * 32]; // 4 x 16KB

    const int tid  = threadIdx.x;
    const int wave = tid >> 6;          // 0..7
    const int lane = tid & 63;
    const int wm   = wave >> 2;         // 0..1 : 128-row output band
    const int wn   = wave & 3;          // 0..3 : 64-col output band

    // bijective XCD swizzle over 252 blocks (252 = 8*31+4, m204 formula);
    // 4 bn-siblings of one A-panel stay consecutive -> same-XCD L2 reuse.
    const int orig = blockIdx.x;
    const int xcd = orig & 7, within = orig >> 3;
    const int wgid = (xcd < 4) ? (xcd * 32 + within)
                               : (128 + (xcd - 4) * 31 + within);
    const int bm = (wgid >> 2) * 256;   // 0..15872 (last block: 128 valid rows)
    const int bn = (wgid & 3) * 256;

    // ---- A reg-staging mapping: 2 threads/row, 16 f32 each ----
    const int rloc = tid >> 1;                       // 0..255 LDS row
    const int asub = tid & 1;                        // 0/1 -> logical segs {0,1}/{2,3}
    int arow = bm + rloc; if (arow > MROWS - 1) arow = MROWS - 1;
    const float* aSrc = A + (size_t)arow * K + asub * 16;
    const int fA = (rloc >> 1) & 3;
    const int wbOff0 = rloc * 32 + ((2 * asub)     ^ fA) * 8;
    const int wbOff1 = rloc * 32 + ((2 * asub + 1) ^ fA) * 8;

    // ---- B gld_lds staging: 1KB/wave-inst = 16 rows x 64B ----
    const int srow = lane >> 2;                      // row in 16-group
    const int sseg = lane & 3;
    const int scol = (sseg ^ ((srow >> 1) & 3)) * 8; // pre-swizzled global col
    const __bf16* gB0 = Bt + (size_t)(bn + (wave * 2 + 0) * 16 + srow) * K + scol;
    const __bf16* gB1 = Bt + (size_t)(bn + (wave * 2 + 1) * 16 + srow) * K + scol;
    const int ldsB0 = (wave * 2 + 0) * 512;
    const int ldsB1 = (wave * 2 + 1) * 512;

    // ---- fragment reads: row = band + i*16 + mrow, seg = quad ^ ((mrow>>1)&3)
    const int mrow = lane & 15, quad = lane >> 4;
    const int swzq = quad ^ ((mrow >> 1) & 3);
    const int rdA = (wm * 128 + mrow) * 32 + swzq * 8;
    const int rdB = (wn * 64  + mrow) * 32 + swzq * 8;

    f32x4 acc[8][4] = {};
    f32x4 gl0[4], gl1[4];

#define ALOAD(G, TT) do { const float* s_ = aSrc + (size_t)(TT) * 32;           \
        G[0] = *(const f32x4*)(s_);      G[1] = *(const f32x4*)(s_ + 4);        \
        G[2] = *(const f32x4*)(s_ + 8);  G[3] = *(const f32x4*)(s_ + 12); } while (0)

#define AWB(G, TT) do { __bf16* ad_ = &As[(TT) & 3][0]; bf16x8 o0_, o1_;        \
        o0_[0]=(__bf16)G[0][0]; o0_[1]=(__bf16)G[0][1]; o0_[2]=(__bf16)G[0][2]; \
        o0_[3]=(__bf16)G[0][3]; o0_[4]=(__bf16)G[1][0]; o0_[5]=(__bf16)G[1][1]; \
        o0_[6]=(__bf16)G[1][2]; o0_[7]=(__bf16)G[1][3];                         \
        o1_[0]=(__bf16)G[2][0]; o1_[1]=(__bf16)G[2][1]; o1_[2]=(__bf16)G[2][2]; \
        o1_[3]=(__bf16)G[2][3]; o1_[4]=(__bf16)G[3][0]; o1_[5]=(__bf16)G[3][1]; \
        o1_[6]=(__bf16)G[3][2]; o1_[7]=(__bf16)G[3][3];                         \
        *(bf16x8*)(ad_ + wbOff0) = o0_; *(bf16x8*)(ad_ + wbOff1) = o1_; } while (0)

#define BSTAGE(TT) do {                                                          \
        gld_lds16(gB0 + (size_t)(TT) * 32, &Bs[(TT) & 3][ldsB0]);                \
        gld_lds16(gB1 + (size_t)(TT) * 32, &Bs[(TT) & 3][ldsB1]); } while (0)

    // ---- prologue: A tiles 0-2 staged, gl1 primed with tile 3, B tiles 0-2 ---
    ALOAD(gl0, 0);
    ALOAD(gl1, 1);
    asm volatile("s_waitcnt vmcnt(4)" ::: "memory");   // tile0 f32 landed
    AWB(gl0, 0);
    ALOAD(gl0, 2);
    asm volatile("s_waitcnt vmcnt(4)" ::: "memory");   // tile1
    AWB(gl1, 1);
    ALOAD(gl1, 3);
    asm volatile("s_waitcnt vmcnt(4)" ::: "memory");   // tile2
    AWB(gl0, 2);
    BSTAGE(0); BSTAGE(1); BSTAGE(2);
    asm volatile("s_waitcnt vmcnt(4) lgkmcnt(0)" ::: "memory"); // A3 + B0 landed
    asm volatile("s_barrier" ::: "memory");

#define KSTEP(T, GI, GC) do {                                                    \
        const __bf16* as_ = &As[(T) & 3][0];                                     \
        const __bf16* bs_ = &Bs[(T) & 3][0];                                     \
        /* ph1: issue A(t+4); counted vmcnt; write-back A(t+3) */                \
        if ((T) + 4 < NT) ALOAD(GI, (T) + 4);                                    \
        if ((T) <= NT - 5)      asm volatile("s_waitcnt vmcnt(6)" ::: "memory"); \
        else if ((T) <= NT - 3) asm volatile("s_waitcnt vmcnt(2)" ::: "memory"); \
        else if ((T) == NT - 2) asm volatile("s_waitcnt vmcnt(0)" ::: "memory"); \
        if ((T) + 3 < NT) AWB(GC, (T) + 3);                                      \
        bf16x8 a_[4], b_[4];                                                     \
        _Pragma("unroll")                                                        \
        for (int i = 0; i < 4; ++i) a_[i] = *(const bf16x8*)&as_[rdA + i * 512]; \
        _Pragma("unroll")                                                        \
        for (int j = 0; j < 4; ++j) b_[j] = *(const bf16x8*)&bs_[rdB + j * 512]; \
        asm volatile("s_waitcnt lgkmcnt(0)" ::: "memory");                       \
        _Pragma("unroll")                                                        \
        for (int i = 0; i < 4; ++i)                                              \
        _Pragma("unroll")                                                        \
            for (int j = 0; j < 4; ++j)                                          \
                acc[i][j] = __builtin_amdgcn_mfma_f32_16x16x32_bf16(             \
                    a_[i], b_[j], acc[i][j], 0, 0, 0);                           \
        asm volatile("s_barrier" ::: "memory");                                  \
        /* ph2: stage B(t+3); a4-7 reads; 16 MFMA */                             \
        if ((T) + 3 < NT) BSTAGE((T) + 3);                                       \
        _Pragma("unroll")                                                        \
        for (int i = 0; i < 4; ++i)                                              \
            a_[i] = *(const bf16x8*)&as_[rdA + 2048 + i * 512];                  \
        asm volatile("s_waitcnt lgkmcnt(0)" ::: "memory");                       \
        _Pragma("unroll")                                                        \
        for (int i = 0; i < 4; ++i)                                              \
        _Pragma("unroll")                                                        \
            for (int j = 0; j < 4; ++j)                                          \
                acc[4 + i][j] = __builtin_amdgcn_mfma_f32_16x16x32_bf16(         \
                    a_[i], b_[j], acc[4 + i][j], 0, 0, 0);                       \
        asm volatile("s_barrier" ::: "memory");                                  \
    } while (0)

#pragma unroll 1
    for (int t = 0; t < NT; t += 2) {
        KSTEP(t,     gl0, gl1);
        KSTEP(t + 1, gl1, gl0);
    }
#undef KSTEP
#undef ALOAD
#undef AWB
#undef BSTAGE

    // epilogue: D[row=quad*4+reg][col=mrow] (m89-verified layout)
    const int Rb = bm + wm * 128 + quad * 4;
    const int Cb = bn + wn * 64 + mrow;
#pragma unroll
    for (int i = 0; i < 8; ++i)
#pragma unroll
        for (int j = 0; j < 4; ++j)
#pragma unroll
            for (int r = 0; r < 4; ++r) {
                const int R = Rb + i * 16 + r;
                if (R < MROWS)
                    H[(size_t)R * OUTDIM + Cb + j * 16] = (__bf16)acc[i][j][r];
            }
}

// ---------------------------------------------------------------------------
// scan pass 1: per (chunk c, batch b): local M/S with zero carry-in; store
// chunk-end values.  256 threads cover all 1024 d (float4 each).
__global__ void scan1(const __bf16* __restrict__ H,
                      f32x4* __restrict__ cM, f32x4* __restrict__ cS,
                      const float* __restrict__ dmp, const float* __restrict__ dsp) {
    const float dm = *dmp, ds = *dsp;
    const int c = blockIdx.x, b = blockIdx.y, tid = threadIdx.x;
    f32x4 M = {}, S = {};
    const __bf16* p = H + ((size_t)b * TDIM + c * CHLEN) * OUTDIM + tid * 4;
#pragma unroll 4
    for (int t = 0; t < CHLEN; ++t) {
        bf16x4 hv = *(const bf16x4*)(p + (size_t)t * OUTDIM);
        f32x4 h; h[0] = hv[0]; h[1] = hv[1]; h[2] = hv[2]; h[3] = hv[3];
        M = dm * (M + h);
        S = ds * (S + h);
    }
    const size_t idx = ((size_t)c * BDIM + b) * 256 + tid;
    cM[idx] = M;
    cS[idx] = S;
}

// ---------------------------------------------------------------------------
// scan pass 2: chunk-end values -> per-chunk carry-INs (in place).
__global__ void scan2(float* __restrict__ cM, float* __restrict__ cS,
                      const float* __restrict__ dmp, const float* __restrict__ dsp) {
    const float dm = *dmp, ds = *dsp;
    float km = 1.f, ks = 1.f;
#pragma unroll
    for (int i = 0; i < CHLEN; ++i) { km *= dm; ks *= ds; }
    const int gid = blockIdx.x * 256 + threadIdx.x;   // 0..32767
    const int b = gid >> 10, d = gid & 1023;
    float tM = 0.f, tS = 0.f;
    for (int c = 0; c < NCHUNK; ++c) {
        const size_t idx = (((size_t)c * BDIM + b) << 10) + d;
        float oM = cM[idx], oS = cS[idx];
        cM[idx] = tM; cS[idx] = tS;
        tM = km * tM + oM;
        tS = ks * tS + oS;
    }
}

// ---------------------------------------------------------------------------
// scan pass 3: recompute with carry-in, write out, accumulate loss; last
// block (device-scope ticket) writes the final loss scalar.
__global__ void scan3(const __bf16* __restrict__ H,
                      const f32x4* __restrict__ cM, const f32x4* __restrict__ cS,
                      const float* __restrict__ normAcc, const float* __restrict__ bias,
                      const float* __restrict__ dmp, const float* __restrict__ dsp,
                      float* __restrict__ out, float* __restrict__ lossAcc,
                      unsigned* __restrict__ ticket) {
    const float dm = *dmp, ds = *dsp;
    const int c = blockIdx.x, b = blockIdx.y, tid = threadIdx.x;
    const size_t cidx = ((size_t)c * BDIM + b) * 256 + tid;
    f32x4 M = cM[cidx];
    f32x4 S = cS[cidx];
    f32x4 nv = *(const f32x4*)(normAcc + tid * 4);
    f32x4 inv;
    inv[0] = 1.f / (nv[0] + 1e-8f); inv[1] = 1.f / (nv[1] + 1e-8f);
    inv[2] = 1.f / (nv[2] + 1e-8f); inv[3] = 1.f / (nv[3] + 1e-8f);
    f32x4 bv = *(const f32x4*)(bias + tid * 4);

    const size_t rowbase = ((size_t)b * TDIM + c * CHLEN) * OUTDIM + tid * 4;
    const __bf16* p = H + rowbase;
    float* o = out + rowbase;
    float loss = 0.f;
#pragma unroll 4
    for (int t = 0; t < CHLEN; ++t) {
        bf16x4 hv = *(const bf16x4*)(p + (size_t)t * OUTDIM);
        f32x4 h; h[0] = hv[0]; h[1] = hv[1]; h[2] = hv[2]; h[3] = hv[3];
        M = dm * (M + h);
        S = ds * (S + h);
        f32x4 r = (M - S) * inv - bv;
        *(f32x4*)(o + (size_t)t * OUTDIM) = r;
        loss += r[0] * r[0] + r[1] * r[1] + r[2] * r[2] + r[3] * r[3];
    }
    __shared__ float red[256];
    red[tid] = loss;
    __syncthreads();
    for (int s = 128; s > 0; s >>= 1) {
        if (tid < s) red[tid] += red[tid + s];
        __syncthreads();
    }
    if (tid == 0) {
        atomicAdd(lossAcc, red[0]);
        __threadfence();
        unsigned t = atomicAdd(ticket, 1u);
        if (t == NCHUNK * BDIM - 1) {
            float total = atomicAdd(lossAcc, 0.0f);   // coherent read
            out[OUT_ELEMS] = 0.5f * total / (float)OUT_ELEMS;
        }
    }
}

// ---------------------------------------------------------------------------
// Workspace layout (bytes):
//   H      (bf16 16000x1024) : 0          .. 32,768,000
//   WBT    (bf16 1024x2048)  : 32,768,000 .. 36,962,304
//   NORM   (f32 1024)        : 36,962,304 .. +4096
//   LOSS   (f32 1)           : 36,966,400
//   TICKET (u32 1)           : 36,966,404
//   CM     (f32 25*32*1024)  : 36,966,656 .. +3,276,800
//   CS                       : 40,243,456 .. +3,276,800   (end 43,520,256)
#define OFF_H      ((size_t)0)
#define OFF_WBT    ((size_t)32768000)
#define OFF_NORM   ((size_t)36962304)
#define OFF_LOSS   ((size_t)36966400)
#define OFF_TICKET ((size_t)36966404)
#define OFF_CM     ((size_t)36966656)
#define OFF_CS     ((size_t)40243456)

extern "C" void kernel_launch(void* const* d_in, const int* in_sizes, int n_in,
                              void* d_out, int out_size, void* d_ws, size_t ws_size,
                              hipStream_t stream) {
    const float* x  = (const float*)d_in[0];
    const float* w  = (const float*)d_in[1];
    const float* bb = (const float*)d_in[2];
    const float* dm = (const float*)d_in[3];
    const float* ds = (const float*)d_in[4];

    char* ws = (char*)d_ws;
    __bf16*   H    = (__bf16*)(ws + OFF_H);
    __bf16*   WBT  = (__bf16*)(ws + OFF_WBT);
    float*    NORM = (float*)(ws + OFF_NORM);
    float*    LOSS = (float*)(ws + OFF_LOSS);
    unsigned* TICK = (unsigned*)(ws + OFF_TICKET);
    f32x4*    CM   = (f32x4*)(ws + OFF_CM);
    f32x4*    CS   = (f32x4*)(ws + OFF_CS);
    float*    out  = (float*)d_out;

    hipMemsetAsync(ws + OFF_NORM, 0, 4096 + 256, stream);   // NORM+LOSS+TICKET

    transpose_w<<<dim3(32, 64), dim3(32, 8), 0, stream>>>(w, WBT, NORM);
    gemm_fused<<<252, 512, 0, stream>>>(x, WBT, H);
    scan1<<<dim3(NCHUNK, BDIM), 256, 0, stream>>>(H, CM, CS, dm, ds);
    scan2<<<128, 256, 0, stream>>>((float*)CM, (float*)CS, dm, ds);
    scan3<<<dim3(NCHUNK, BDIM), 256, 0, stream>>>(H, CM, CS, NORM, bb, dm, ds,
                                                  out, LOSS, TICK);
}

// Round 5
// 333.803 us; speedup vs baseline: 1.0287x; 1.0287x over previous
//
#include <hip/hip_runtime.h>

// ---------------------------------------------------------------------------
// STCAOutputLayer: h = x@w (bf16 MFMA GEMM); E==0 identically (spk never set),
// out[b,t,d] = (M_t - S_t)*inv_norm[d] - bias[d],
// M_t = dm*(M_{t-1}+h_t), S_t = ds*(S_{t-1}+h_t); loss = 0.5*mean(out^2).
// Shapes: B=32 T=500 IN=2048 OUT=1024; M=B*T=16000, N=1024, K=2048.
//
// R3-R6: four self-designed schedules all 20-34% MfmaUtil. R7: faithful port
// of the verified 256^2 8-phase template (m201, 62% MfmaUtil):
//   BM=BN=256, BK=64, 8 waves, 2 LDS dbufs (128KB), 4 phases/K-tile,
//   16 MFMA/phase with setprio(1), ds_reads issued BEFORE the phase barrier
//   and guarded after it only by the wave's OWN lgkm (compiler) -> first
//   wave released starts MFMAs while LDS pipe serves the others.
//   Wave tile 128x64 as half-pairs: phase (hm,hn) = (0,0),(0,1),(1,1),(1,0)
//   -> 12/4/8/4 ds_reads per phase (template's counts), single a/b reg sets.
//   Half-tile stage order A0,B0,B1,A1 (2 gld_lds/wave/phase); ledger-derived
//   counted waits: vmcnt(4) at ph1,ph2,ph4 (tail 2->0); never drains.
//   LDS as [128][32] kk-subtiles w/ XOR-4 swizzle (measured 0 conflicts).
// ---------------------------------------------------------------------------

typedef __bf16 bf16x8 __attribute__((ext_vector_type(8)));
typedef __bf16 bf16x4 __attribute__((ext_vector_type(4)));
typedef float  f32x4  __attribute__((ext_vector_type(4)));

#define BDIM 32
#define TDIM 500
#define INDIM 2048
#define OUTDIM 1024
#define MROWS 16000            // B*T
#define NCHUNK 25              // scan chunks
#define CHLEN 20               // 25*20 = 500
#define OUT_ELEMS 16384000     // B*T*OUT

// ---- global -> LDS async copy, 16B per lane, LDS dest = base + lane*16 ----
__device__ __forceinline__ void gld_lds16(const void* g, void* l) {
    __builtin_amdgcn_global_load_lds(
        (const __attribute__((address_space(1))) unsigned int*)g,
        (__attribute__((address_space(3))) unsigned int*)l, 16, 0, 0);
}

// ---------------------------------------------------------------------------
// fp32 -> bf16 convert of x (pure elementwise). 8 elems / thread.
__global__ void convert_x(const float* __restrict__ x, __bf16* __restrict__ xb) {
    size_t i = ((size_t)blockIdx.x * 256 + threadIdx.x) * 8;
    float4 a = *(const float4*)(x + i);
    float4 b = *(const float4*)(x + i + 4);
    bf16x8 o;
    o[0] = (__bf16)a.x; o[1] = (__bf16)a.y; o[2] = (__bf16)a.z; o[3] = (__bf16)a.w;
    o[4] = (__bf16)b.x; o[5] = (__bf16)b.y; o[6] = (__bf16)b.z; o[7] = (__bf16)b.w;
    *(bf16x8*)(xb + i) = o;
}

// ---------------------------------------------------------------------------
// w [K=2048][N=1024] fp32 -> wbt [N][K] bf16, with fused norm[d]=sum_c w^2
__global__ void transpose_w(const float* __restrict__ w, __bf16* __restrict__ wbt,
                            float* __restrict__ normAcc) {
    __shared__ float tile[32][33];
    __shared__ float red[8][33];
    const int tx = threadIdx.x;        // 0..31
    const int ty = threadIdx.y;        // 0..7
    const int d0 = blockIdx.x * 32;    // N tile
    const int c0 = blockIdx.y * 32;    // K tile
    float s = 0.f;
#pragma unroll
    for (int i = 0; i < 4; ++i) {
        int c = c0 + ty + i * 8;
        float v = w[(size_t)c * OUTDIM + d0 + tx];
        tile[ty + i * 8][tx] = v;
        s += v * v;
    }
    red[ty][tx] = s;
    __syncthreads();
#pragma unroll
    for (int i = 0; i < 4; ++i) {
        int d = d0 + ty + i * 8;
        wbt[(size_t)d * INDIM + c0 + tx] = (__bf16)tile[tx][ty + i * 8];
    }
    if (ty == 0) {
        float t = red[0][tx] + red[1][tx] + red[2][tx] + red[3][tx]
                + red[4][tx] + red[5][tx] + red[6][tx] + red[7][tx];
        atomicAdd(&normAcc[d0 + tx], t);
    }
}

// ---------------------------------------------------------------------------
// GEMM: H[m][n] = sum_k A[m][k]*Bt[n][k], bf16 in/out (fp32 acc).
// 8-phase template; see header. Wave (wm=wave>>2, wn=wave&3) output:
// rows {bm + hm*128 + wm*64 +[0,64)}, cols {bn + hn*128 + wn*32 +[0,32)}.
// LDS: SA/SB [dbuf][half][kk][128*32] bf16; one kk-subtile = 8KB, rows 64B.
// Stage: half = 2 gld_lds/wave (kk=0,1); instr covers rows [wave*16,+16),
// lane -> (row=lane>>2, seg=lane&3), global col pre-swizzled seg^((row>>1)&3).
// Ledger (steady, queue oldest->new; 2 instrs per half):
//  ph1 wait: [B1(t),A1(t),A0(t+1)]=6 -> vmcnt(4) lands B1(t) for ph2 reads
//  ph2 wait: [A1(t),A0(t+1),B0(t+1)]=6 -> vmcnt(4) lands A1(t) for ph3
//  ph3: no wait (ph4 re-reads B0(t), resident since ph1)
//  ph4 wait: [A0,B0,B1,A1](t+1)=8 -> vmcnt(4) lands A0,B0 for ph1(t+1)
// Tail t=NT-1 (no stages): ph1 vmcnt(2), ph2 vmcnt(0), ph4 none.
// WAR safe: stages during tile t write buf[(t+1)&1]; reads of that buffer's
// previous generation ended >=4 barriers earlier.
__global__ __launch_bounds__(512, 2) void gemm_bf16(
    const __bf16* __restrict__ A,   // [16000][2048]  (xb, lives in d_out)
    const __bf16* __restrict__ Bt,  // [1024][2048]
    __bf16* __restrict__ H)         // [16000][1024]
{
    constexpr int K  = INDIM;
    constexpr int NT = K / 64;                         // 32 K-tiles
    __shared__ __align__(16) __bf16 SA[2][2][2][4096]; // 64 KB
    __shared__ __align__(16) __bf16 SB[2][2][2][4096]; // 64 KB

    const int tid  = threadIdx.x;
    const int wave = tid >> 6;          // 0..7
    const int lane = tid & 63;
    const int wm   = wave >> 2;         // 0..1
    const int wn   = wave & 3;          // 0..3

    // bijective XCD swizzle over 252 blocks (252 = 8*31+4, m204 formula)
    const int orig = blockIdx.x;
    const int xcd = orig & 7, within = orig >> 3;
    const int wgid = (xcd < 4) ? (xcd * 32 + within)
                               : (128 + (xcd - 4) * 31 + within);
    const int bm = (wgid >> 2) * 256;   // 0..15872 (last block: 128 valid rows)
    const int bn = (wgid & 3) * 256;

    // staging lane mapping (one gld instr = 16 rows x 64B)
    const int srow = lane >> 2;
    const int sseg = lane & 3;
    const int scol = (sseg ^ ((srow >> 1) & 3)) * 8;   // pre-swizzled col (elems)
    int ra0 = bm +       wave * 16 + srow; if (ra0 > MROWS - 1) ra0 = MROWS - 1;
    int ra1 = bm + 128 + wave * 16 + srow; if (ra1 > MROWS - 1) ra1 = MROWS - 1;
    const __bf16* pA0 = A  + (size_t)ra0 * K + scol;
    const __bf16* pA1 = A  + (size_t)ra1 * K + scol;
    const __bf16* pB0 = Bt + (size_t)(bn +       wave * 16 + srow) * K + scol;
    const __bf16* pB1 = Bt + (size_t)(bn + 128 + wave * 16 + srow) * K + scol;
    const int sdst = wave * 512;                       // elems

    // fragment reads within a [128][32] subtile
    const int mrow = lane & 15, quad = lane >> 4;
    const int swzq = quad ^ ((mrow >> 1) & 3);
    const int rdA = (wm * 64 + mrow) * 32 + swzq * 8;
    const int rdB = (wn * 32 + mrow) * 32 + swzq * 8;

    f32x4 acc[8][4] = {};
    bf16x8 a[4][2], b[2][2];

#define STG_A(NB, HH, T1) do { const __bf16* p_ = (HH) ? pA1 : pA0;            \
        gld_lds16(p_ + (size_t)(T1) * 64,      &SA[NB][HH][0][sdst]);          \
        gld_lds16(p_ + (size_t)(T1) * 64 + 32, &SA[NB][HH][1][sdst]); } while (0)
#define STG_B(NB, HH, T1) do { const __bf16* p_ = (HH) ? pB1 : pB0;            \
        gld_lds16(p_ + (size_t)(T1) * 64,      &SB[NB][HH][0][sdst]);          \
        gld_lds16(p_ + (size_t)(T1) * 64 + 32, &SB[NB][HH][1][sdst]); } while (0)
#define RD_A(BUF, HH) do { _Pragma("unroll")                                   \
        for (int i = 0; i < 4; ++i) {                                          \
            a[i][0] = *(const bf16x8*)&SA[BUF][HH][0][rdA + i * 512];          \
            a[i][1] = *(const bf16x8*)&SA[BUF][HH][1][rdA + i * 512]; } } while (0)
#define RD_B(BUF, HH) do { _Pragma("unroll")                                   \
        for (int j = 0; j < 2; ++j) {                                          \
            b[j][0] = *(const bf16x8*)&SB[BUF][HH][0][rdB + j * 512];          \
            b[j][1] = *(const bf16x8*)&SB[BUF][HH][1][rdB + j * 512]; } } while (0)
#define MM(HM, HN) do { __builtin_amdgcn_s_setprio(1);                         \
        _Pragma("unroll")                                                      \
        for (int i = 0; i < 4; ++i)                                            \
        _Pragma("unroll")                                                      \
        for (int j = 0; j < 2; ++j) {                                          \
            acc[(HM)*4+i][(HN)*2+j] = __builtin_amdgcn_mfma_f32_16x16x32_bf16( \
                a[i][0], b[j][0], acc[(HM)*4+i][(HN)*2+j], 0, 0, 0);           \
            acc[(HM)*4+i][(HN)*2+j] = __builtin_amdgcn_mfma_f32_16x16x32_bf16( \
                a[i][1], b[j][1], acc[(HM)*4+i][(HN)*2+j], 0, 0, 0); }         \
        __builtin_amdgcn_s_setprio(0); } while (0)

#define TILE(T, CUR, NB) do {                                                  \
        const bool st_   = (T) + 1 < NT;                                       \
        const bool last_ = (T) == NT - 1;                                      \
        /* ph1: (hm0,hn0) */                                                   \
        RD_A(CUR, 0); RD_B(CUR, 0);                                            \
        if (st_) STG_A(NB, 0, (T) + 1);                                        \
        if (!last_) asm volatile("s_waitcnt vmcnt(4)" ::: "memory");           \
        else        asm volatile("s_waitcnt vmcnt(2)" ::: "memory");           \
        asm volatile("s_barrier" ::: "memory");                                \
        MM(0, 0);                                                              \
        /* ph2: (hm0,hn1) — a held */                                          \
        RD_B(CUR, 1);                                                          \
        if (st_) STG_B(NB, 0, (T) + 1);                                        \
        if (!last_) asm volatile("s_waitcnt vmcnt(4)" ::: "memory");           \
        else        asm volatile("s_waitcnt vmcnt(0)" ::: "memory");           \
        asm volatile("s_barrier" ::: "memory");                                \
        MM(0, 1);                                                              \
        /* ph3: (hm1,hn1) — b held */                                          \
        RD_A(CUR, 1);                                                          \
        if (st_) STG_B(NB, 1, (T) + 1);                                        \
        asm volatile("s_barrier" ::: "memory");                                \
        MM(1, 1);                                                              \
        /* ph4: (hm1,hn0) — B0 re-read */                                      \
        RD_B(CUR, 0);                                                          \
        if (st_) STG_A(NB, 1, (T) + 1);                                        \
        if (st_) asm volatile("s_waitcnt vmcnt(4)" ::: "memory");              \
        asm volatile("s_barrier" ::: "memory");                                \
        MM(1, 0);                                                              \
    } while (0)

    // prologue: tile0's 4 halves in first-use order; land A0,B0
    STG_A(0, 0, 0); STG_B(0, 0, 0); STG_B(0, 1, 0); STG_A(0, 1, 0);
    asm volatile("s_waitcnt vmcnt(4)" ::: "memory");
    asm volatile("s_barrier" ::: "memory");

#pragma unroll 1
    for (int tt = 0; tt < NT; tt += 2) {
        TILE(tt,     0, 1);
        TILE(tt + 1, 1, 0);
    }
#undef TILE
#undef MM
#undef RD_B
#undef RD_A
#undef STG_B
#undef STG_A

    // epilogue: D[row=quad*4+r][col=mrow] per frag (m89-verified layout)
#pragma unroll
    for (int hm = 0; hm < 2; ++hm)
#pragma unroll
        for (int i = 0; i < 4; ++i)
#pragma unroll
            for (int hn = 0; hn < 2; ++hn)
#pragma unroll
                for (int j = 0; j < 2; ++j)
#pragma unroll
                    for (int r = 0; r < 4; ++r) {
                        const int R = bm + hm * 128 + wm * 64 + i * 16 + quad * 4 + r;
                        const int C = bn + hn * 128 + wn * 32 + j * 16 + mrow;
                        if (R < MROWS)
                            H[(size_t)R * OUTDIM + C] = (__bf16)acc[hm * 4 + i][hn * 2 + j][r];
                    }
}

// ---------------------------------------------------------------------------
// scan pass 1: per (chunk c, batch b): local M/S with zero carry-in; store
// chunk-end values.  256 threads cover all 1024 d (float4 each).
__global__ void scan1(const __bf16* __restrict__ H,
                      f32x4* __restrict__ cM, f32x4* __restrict__ cS,
                      const float* __restrict__ dmp, const float* __restrict__ dsp) {
    const float dm = *dmp, ds = *dsp;
    const int c = blockIdx.x, b = blockIdx.y, tid = threadIdx.x;
    f32x4 M = {}, S = {};
    const __bf16* p = H + ((size_t)b * TDIM + c * CHLEN) * OUTDIM + tid * 4;
#pragma unroll 4
    for (int t = 0; t < CHLEN; ++t) {
        bf16x4 hv = *(const bf16x4*)(p + (size_t)t * OUTDIM);
        f32x4 h; h[0] = hv[0]; h[1] = hv[1]; h[2] = hv[2]; h[3] = hv[3];
        M = dm * (M + h);
        S = ds * (S + h);
    }
    const size_t idx = ((size_t)c * BDIM + b) * 256 + tid;
    cM[idx] = M;
    cS[idx] = S;
}

// ---------------------------------------------------------------------------
// scan pass 2: chunk-end values -> per-chunk carry-INs (in place).
__global__ void scan2(float* __restrict__ cM, float* __restrict__ cS,
                      const float* __restrict__ dmp, const float* __restrict__ dsp) {
    const float dm = *dmp, ds = *dsp;
    float km = 1.f, ks = 1.f;
#pragma unroll
    for (int i = 0; i < CHLEN; ++i) { km *= dm; ks *= ds; }
    const int gid = blockIdx.x * 256 + threadIdx.x;   // 0..32767
    const int b = gid >> 10, d = gid & 1023;
    float tM = 0.f, tS = 0.f;
    for (int c = 0; c < NCHUNK; ++c) {
        const size_t idx = (((size_t)c * BDIM + b) << 10) + d;
        float oM = cM[idx], oS = cS[idx];
        cM[idx] = tM; cS[idx] = tS;
        tM = km * tM + oM;
        tS = ks * tS + oS;
    }
}

// ---------------------------------------------------------------------------
// scan pass 3: recompute with carry-in, write out, accumulate loss; last
// block (device-scope ticket) writes the final loss scalar.
__global__ void scan3(const __bf16* __restrict__ H,
                      const f32x4* __restrict__ cM, const f32x4* __restrict__ cS,
                      const float* __restrict__ normAcc, const float* __restrict__ bias,
                      const float* __restrict__ dmp, const float* __restrict__ dsp,
                      float* __restrict__ out, float* __restrict__ lossAcc,
                      unsigned* __restrict__ ticket) {
    const float dm = *dmp, ds = *dsp;
    const int c = blockIdx.x, b = blockIdx.y, tid = threadIdx.x;
    const size_t cidx = ((size_t)c * BDIM + b) * 256 + tid;
    f32x4 M = cM[cidx];
    f32x4 S = cS[cidx];
    f32x4 nv = *(const f32x4*)(normAcc + tid * 4);
    f32x4 inv;
    inv[0] = 1.f / (nv[0] + 1e-8f); inv[1] = 1.f / (nv[1] + 1e-8f);
    inv[2] = 1.f / (nv[2] + 1e-8f); inv[3] = 1.f / (nv[3] + 1e-8f);
    f32x4 bv = *(const f32x4*)(bias + tid * 4);

    const size_t rowbase = ((size_t)b * TDIM + c * CHLEN) * OUTDIM + tid * 4;
    const __bf16* p = H + rowbase;
    float* o = out + rowbase;
    float loss = 0.f;
#pragma unroll 4
    for (int t = 0; t < CHLEN; ++t) {
        bf16x4 hv = *(const bf16x4*)(p + (size_t)t * OUTDIM);
        f32x4 h; h[0] = hv[0]; h[1] = hv[1]; h[2] = hv[2]; h[3] = hv[3];
        M = dm * (M + h);
        S = ds * (S + h);
        f32x4 r = (M - S) * inv - bv;
        *(f32x4*)(o + (size_t)t * OUTDIM) = r;
        loss += r[0] * r[0] + r[1] * r[1] + r[2] * r[2] + r[3] * r[3];
    }
    __shared__ float red[256];
    red[tid] = loss;
    __syncthreads();
    for (int s = 128; s > 0; s >>= 1) {
        if (tid < s) red[tid] += red[tid + s];
        __syncthreads();
    }
    if (tid == 0) {
        atomicAdd(lossAcc, red[0]);
        __threadfence();
        unsigned t = atomicAdd(ticket, 1u);
        if (t == NCHUNK * BDIM - 1) {
            float total = atomicAdd(lossAcc, 0.0f);   // coherent read
            out[OUT_ELEMS] = 0.5f * total / (float)OUT_ELEMS;
        }
    }
}

// ---------------------------------------------------------------------------
// Workspace layout (bytes):
//   H      (bf16 16000x1024) : 0          .. 32,768,000
//   WBT    (bf16 1024x2048)  : 32,768,000 .. 36,962,304
//   NORM   (f32 1024)        : 36,962,304 .. +4096
//   LOSS   (f32 1)           : 36,966,400
//   TICKET (u32 1)           : 36,966,404
//   CM     (f32 25*32*1024)  : 36,966,656 .. +3,276,800
//   CS                       : 40,243,456 .. +3,276,800   (end 43,520,256)
// xb (bf16 x) lives in d_out (exactly 65,536,000 B) until scan3 overwrites it.
#define OFF_H      ((size_t)0)
#define OFF_WBT    ((size_t)32768000)
#define OFF_NORM   ((size_t)36962304)
#define OFF_LOSS   ((size_t)36966400)
#define OFF_TICKET ((size_t)36966404)
#define OFF_CM     ((size_t)36966656)
#define OFF_CS     ((size_t)40243456)

extern "C" void kernel_launch(void* const* d_in, const int* in_sizes, int n_in,
                              void* d_out, int out_size, void* d_ws, size_t ws_size,
                              hipStream_t stream) {
    const float* x  = (const float*)d_in[0];
    const float* w  = (const float*)d_in[1];
    const float* bb = (const float*)d_in[2];
    const float* dm = (const float*)d_in[3];
    const float* ds = (const float*)d_in[4];

    char* ws = (char*)d_ws;
    __bf16*   H    = (__bf16*)(ws + OFF_H);
    __bf16*   WBT  = (__bf16*)(ws + OFF_WBT);
    float*    NORM = (float*)(ws + OFF_NORM);
    float*    LOSS = (float*)(ws + OFF_LOSS);
    unsigned* TICK = (unsigned*)(ws + OFF_TICKET);
    f32x4*    CM   = (f32x4*)(ws + OFF_CM);
    f32x4*    CS   = (f32x4*)(ws + OFF_CS);
    __bf16*   XB   = (__bf16*)d_out;          // scratch: bf16 x (exact fit)
    float*    out  = (float*)d_out;

    hipMemsetAsync(ws + OFF_NORM, 0, 4096 + 256, stream);   // NORM+LOSS+TICKET

    convert_x<<<16000, 256, 0, stream>>>(x, XB);
    transpose_w<<<dim3(32, 64), dim3(32, 8), 0, stream>>>(w, WBT, NORM);
    gemm_bf16<<<252, 512, 0, stream>>>(XB, WBT, H);
    scan1<<<dim3(NCHUNK, BDIM), 256, 0, stream>>>(H, CM, CS, dm, ds);
    scan2<<<128, 256, 0, stream>>>((float*)CM, (float*)CS, dm, ds);
    scan3<<<dim3(NCHUNK, BDIM), 256, 0, stream>>>(H, CM, CS, NORM, bb, dm, ds,
                                                  out, LOSS, TICK);
}